// Round 1
// baseline (300.444 us; speedup 1.0000x reference)
//
#include <hip/hip_runtime.h>

#define IH 126
#define IW 126
#define OH 124
#define OW 124

// ---------------------------------------------------------------- conv_in
// (1,3,128,128) -> (1,64,126,126), 3x3 valid conv. 55 MFLOP, naive is fine.
__global__ __launch_bounds__(256) void conv_in_kernel(
    const float* __restrict__ x, const float* __restrict__ w,
    const float* __restrict__ b, float* __restrict__ y)
{
  int pix = blockIdx.x * 256 + threadIdx.x;
  if (pix >= IH * IW) return;
  int oc = blockIdx.y;                 // wave-uniform -> weights become s_loads
  int h  = pix / IW;
  int wc = pix - h * IW;
  const float* wp = w + oc * 27;
  float acc = b[oc];
#pragma unroll
  for (int ci = 0; ci < 3; ci++)
#pragma unroll
    for (int ky = 0; ky < 3; ky++)
#pragma unroll
      for (int kx = 0; kx < 3; kx++)
        acc = fmaf(x[ci * 128 * 128 + (h + ky) * 128 + (wc + kx)],
                   wp[ci * 9 + ky * 3 + kx], acc);
  y[oc * IH * IW + pix] = acc;
}

// ---------------------------------------------------------------- involution
// One block = 8x8 spatial tile, all 64 channels, fully fused:
//   t = ReLU(BN(Wr.x))  ->  w = Ws.t + bs (per-thread regs)  ->  7x7 einsum
// 512 threads: p = tid&63 (position), q = (tid>>6)&3 (group), half = tid>>8.
__global__ __launch_bounds__(512) void inv_kernel(
    const float* __restrict__ x, float* __restrict__ y,
    const float* __restrict__ wr, const float* __restrict__ br,
    const float* __restrict__ gam, const float* __restrict__ bet,
    const float* __restrict__ mu, const float* __restrict__ var,
    const float* __restrict__ wspan, const float* __restrict__ bspan)
{
  // [pos][ch] layout, ch padded 64->68: b128 channel reads start at bank
  // 4*(pos mod 8) -> 8 distinct quad-banks across a wave = conflict-optimal.
  __shared__ __align__(16) float xs[196][68];   // 53,312 B
  __shared__ __align__(16) float ts[64][20];    //  5,120 B  (stride 20: b128-aligned, 8 bank starts)

  int tid = threadIdx.x;
  int bx = blockIdx.x & 15, by = blockIdx.x >> 4;
  int x0 = bx * 8 - 3, y0 = by * 8 - 3;

  // ---- stage x halo (14x14 x 64ch), zero-padded
  for (int i = tid; i < 64 * 196; i += 512) {
    int c = i / 196;
    int pos = i - c * 196;
    int r = pos / 14;
    int col = pos - r * 14;
    int gy = y0 + r, gx = x0 + col;
    float v = 0.f;
    if (gy >= 0 && gy < IH && gx >= 0 && gx < IW)
      v = x[c * IH * IW + gy * IW + gx];
    xs[pos][c] = v;
  }
  __syncthreads();

  int p = tid & 63;
  int q = (tid >> 6) & 3;
  int half = tid >> 8;
  int px = p & 7, py = p >> 3;
  int pc = (py + 3) * 14 + (px + 3);   // center position in halo tile

  // ---- t phase: 2 reduced channels per thread
  int cr0 = (q * 2 + half) * 2;
  int cr0u = __builtin_amdgcn_readfirstlane(cr0);  // force scalar weight path
  const float* wr0 = wr + cr0u * 64;
  float a0 = 0.f, a1 = 0.f;
#pragma unroll
  for (int ci = 0; ci < 64; ci += 4) {
    float4 xv = *(const float4*)&xs[pc][ci];
    a0 = fmaf(xv.x, wr0[ci + 0], a0);
    a0 = fmaf(xv.y, wr0[ci + 1], a0);
    a0 = fmaf(xv.z, wr0[ci + 2], a0);
    a0 = fmaf(xv.w, wr0[ci + 3], a0);
    a1 = fmaf(xv.x, wr0[64 + ci + 0], a1);
    a1 = fmaf(xv.y, wr0[64 + ci + 1], a1);
    a1 = fmaf(xv.z, wr0[64 + ci + 2], a1);
    a1 = fmaf(xv.w, wr0[64 + ci + 3], a1);
  }
  {
    float s0 = gam[cr0u]     * rsqrtf(var[cr0u]     + 1e-5f);
    float s1 = gam[cr0u + 1] * rsqrtf(var[cr0u + 1] + 1e-5f);
    float t0 = (a0 + br[cr0u]     - mu[cr0u])     * s0 + bet[cr0u];
    float t1 = (a1 + br[cr0u + 1] - mu[cr0u + 1]) * s1 + bet[cr0u + 1];
    ts[p][cr0u + 0] = fmaxf(t0, 0.f);
    ts[p][cr0u + 1] = fmaxf(t1, 0.f);
  }
  __syncthreads();

  // ---- kernel-generation phase: 49 weights for (group q, position p)
  float tv[16];
#pragma unroll
  for (int i = 0; i < 16; i += 4) {
    float4 t4 = *(const float4*)&ts[p][i];
    tv[i] = t4.x; tv[i + 1] = t4.y; tv[i + 2] = t4.z; tv[i + 3] = t4.w;
  }
  int gu = __builtin_amdgcn_readfirstlane(q);
  const float* wsp = wspan + gu * 49 * 16;   // uniform -> s_load_dwordx16 runs
  const float* bsp = bspan + gu * 49;
  float wv[49];
#pragma unroll
  for (int j = 0; j < 49; j++) {
    float a = bsp[j];
#pragma unroll
    for (int cr = 0; cr < 16; cr++)
      a = fmaf(tv[cr], wsp[j * 16 + cr], a);
    wv[j] = a;
  }

  // ---- einsum: out[c] = sum_k wv[k] * x[c, p+k], 8 channels per thread
  int cbase = q * 16 + half * 8;
  float acc[8];
#pragma unroll
  for (int i = 0; i < 8; i++) acc[i] = 0.f;
#pragma unroll
  for (int ky = 0; ky < 7; ky++) {
#pragma unroll
    for (int kx = 0; kx < 7; kx++) {
      float wj = wv[ky * 7 + kx];
      int pidx = (py + ky) * 14 + (px + kx);
      float4 m0 = *(const float4*)&xs[pidx][cbase];
      float4 m1 = *(const float4*)&xs[pidx][cbase + 4];
      acc[0] = fmaf(wj, m0.x, acc[0]);
      acc[1] = fmaf(wj, m0.y, acc[1]);
      acc[2] = fmaf(wj, m0.z, acc[2]);
      acc[3] = fmaf(wj, m0.w, acc[3]);
      acc[4] = fmaf(wj, m1.x, acc[4]);
      acc[5] = fmaf(wj, m1.y, acc[5]);
      acc[6] = fmaf(wj, m1.z, acc[6]);
      acc[7] = fmaf(wj, m1.w, acc[7]);
    }
  }
  int gy = by * 8 + py, gx = bx * 8 + px;
  if (gy < IH && gx < IW) {
#pragma unroll
    for (int i = 0; i < 8; i++)
      y[(cbase + i) * IH * IW + gy * IW + gx] = fmaxf(acc[i], 0.f);  // ReLU
  }
}

// ---------------------------------------------------------------- conv_out prep
// w (128,64,3,3) -> wt[k][ci][oc] so a wave's 4 output channels are contiguous.
__global__ __launch_bounds__(256) void transpose_w_kernel(
    const float* __restrict__ w, float* __restrict__ wt)
{
  int i = blockIdx.x * 256 + threadIdx.x;
  if (i >= 128 * 64 * 9) return;
  int oc = i / 576;
  int rem = i - oc * 576;
  int ci = rem / 9;
  int k = rem - ci * 9;
  wt[(k * 64 + ci) * 128 + oc] = w[i];
}

// ---------------------------------------------------------------- conv_out
// (64,126,126) -> (128,124,124) 3x3 valid. 8x8 tile, 32 och per block
// (4 per wave, uniform -> weights via s_load_dwordx4). 1024 blocks = 32 waves/CU.
__global__ __launch_bounds__(512) void conv_out_kernel(
    const float* __restrict__ x, const float* __restrict__ wt,
    const float* __restrict__ b, float* __restrict__ y)
{
  __shared__ __align__(16) float xs[100][68];  // 27,200 B
  int tid = threadIdx.x;
  int bx = blockIdx.x & 15, by = blockIdx.x >> 4;
  int oy0 = by * 8, ox0 = bx * 8;

  for (int i = tid; i < 64 * 100; i += 512) {
    int c = i / 100;
    int pos = i - c * 100;
    int r = pos / 10;
    int col = pos - r * 10;
    int gy = oy0 + r, gx = ox0 + col;
    float v = 0.f;
    if (gy < IH && gx < IW) v = x[c * IH * IW + gy * IW + gx];
    xs[pos][c] = v;
  }
  __syncthreads();

  int p = tid & 63;
  int px = p & 7, py = p >> 3;
  int ochq = __builtin_amdgcn_readfirstlane(tid >> 6);  // wave id 0..7
  int och0 = blockIdx.y * 32 + ochq * 4;

  float acc0 = b[och0 + 0], acc1 = b[och0 + 1];
  float acc2 = b[och0 + 2], acc3 = b[och0 + 3];
#pragma unroll
  for (int ky = 0; ky < 3; ky++) {
#pragma unroll
    for (int kx = 0; kx < 3; kx++) {
      int k = ky * 3 + kx;
      const float* wp = wt + k * 64 * 128 + och0;
      int pidx = (py + ky) * 10 + (px + kx);
#pragma unroll
      for (int ci = 0; ci < 64; ci += 4) {
        float4 xq = *(const float4*)&xs[pidx][ci];
        float4 w0 = *(const float4*)(wp + (ci + 0) * 128);
        float4 w1 = *(const float4*)(wp + (ci + 1) * 128);
        float4 w2 = *(const float4*)(wp + (ci + 2) * 128);
        float4 w3 = *(const float4*)(wp + (ci + 3) * 128);
        acc0 = fmaf(xq.x, w0.x, acc0); acc1 = fmaf(xq.x, w0.y, acc1);
        acc2 = fmaf(xq.x, w0.z, acc2); acc3 = fmaf(xq.x, w0.w, acc3);
        acc0 = fmaf(xq.y, w1.x, acc0); acc1 = fmaf(xq.y, w1.y, acc1);
        acc2 = fmaf(xq.y, w1.z, acc2); acc3 = fmaf(xq.y, w1.w, acc3);
        acc0 = fmaf(xq.z, w2.x, acc0); acc1 = fmaf(xq.z, w2.y, acc1);
        acc2 = fmaf(xq.z, w2.z, acc2); acc3 = fmaf(xq.z, w2.w, acc3);
        acc0 = fmaf(xq.w, w3.x, acc0); acc1 = fmaf(xq.w, w3.y, acc1);
        acc2 = fmaf(xq.w, w3.z, acc2); acc3 = fmaf(xq.w, w3.w, acc3);
      }
    }
  }
  int oy = oy0 + py, ox = ox0 + px;
  if (oy < OH && ox < OW) {
    y[(och0 + 0) * OH * OW + oy * OW + ox] = acc0;
    y[(och0 + 1) * OH * OW + oy * OW + ox] = acc1;
    y[(och0 + 2) * OH * OW + oy * OW + ox] = acc2;
    y[(och0 + 3) * OH * OW + oy * OW + ox] = acc3;
  }
}

// ---------------------------------------------------------------- launch
extern "C" void kernel_launch(void* const* d_in, const int* in_sizes, int n_in,
                              void* d_out, int out_size, void* d_ws, size_t ws_size,
                              hipStream_t stream)
{
  const float* input = (const float*)d_in[0];
  const float* ciw   = (const float*)d_in[1];
  const float* cib   = (const float*)d_in[2];
  const float* wred  = (const float*)d_in[3];
  const float* bred  = (const float*)d_in[4];
  const float* gam   = (const float*)d_in[5];
  const float* bet   = (const float*)d_in[6];
  const float* mu    = (const float*)d_in[7];
  const float* var   = (const float*)d_in[8];
  const float* wspan = (const float*)d_in[9];
  const float* bspan = (const float*)d_in[10];
  const float* cow   = (const float*)d_in[11];
  const float* cob   = (const float*)d_in[12];
  float* out = (float*)d_out;

  float* bufA = (float*)d_ws;                 // 64*126*126 = 1,016,064 floats
  float* bufB = bufA + (1 << 20);             // @ 4 MiB
  float* wt   = bufA + (1 << 21);             // @ 8 MiB, 73,728 floats

  transpose_w_kernel<<<288, 256, 0, stream>>>(cow, wt);
  conv_in_kernel<<<dim3(63, 64), 256, 0, stream>>>(input, ciw, cib, bufA);

  float* cur = bufA; float* nxt = bufB;
  for (int i = 0; i < 6; i++) {
    inv_kernel<<<256, 512, 0, stream>>>(cur, nxt,
        wred + i * 16 * 64, bred + i * 16, gam + i * 16, bet + i * 16,
        mu + i * 16, var + i * 16, wspan + i * 196 * 16, bspan + i * 196);
    float* t = cur; cur = nxt; nxt = t;
  }
  conv_out_kernel<<<dim3(256, 4), 512, 0, stream>>>(cur, wt, cob, out);
}

// Round 2
// 254.618 us; speedup vs baseline: 1.1800x; 1.1800x over previous
//
#include <hip/hip_runtime.h>

#define IH 126
#define IW 126
#define HW 15876      // 126*126
#define OH 124
#define OW 124
#define OHW 15376     // 124*124

// ---------------------------------------------------------------- conv_in
// (1,3,128,128) -> (1,64,126,126), 3x3 valid conv. 55 MFLOP, naive is fine.
__global__ __launch_bounds__(256) void conv_in_kernel(
    const float* __restrict__ x, const float* __restrict__ w,
    const float* __restrict__ b, float* __restrict__ y)
{
  int pix = blockIdx.x * 256 + threadIdx.x;
  if (pix >= HW) return;
  int oc = blockIdx.y;                 // wave-uniform -> weights become s_loads
  int h  = pix / IW;
  int wc = pix - h * IW;
  const float* wp = w + oc * 27;
  float acc = b[oc];
#pragma unroll
  for (int ci = 0; ci < 3; ci++)
#pragma unroll
    for (int ky = 0; ky < 3; ky++)
#pragma unroll
      for (int kx = 0; kx < 3; kx++)
        acc = fmaf(x[ci * 128 * 128 + (h + ky) * 128 + (wc + kx)],
                   wp[ci * 9 + ky * 3 + kx], acc);
  y[oc * HW + pix] = acc;
}

// ---------------------------------------------------------------- involution v2
// Tile 8 wide x 4 tall. Grid 16x32 = 512 blocks -> 2 blocks/CU.
// Phase A: stage halo 14x10 x 64ch into xs[pos][65]  (writes lane-stride-65: free)
// Phase B: t[32px][16cr] = ReLU(BN(Wr.x))            (lane = pixel(+cr half))
// Phase C: wv[g][k][col][row] = Ws.t + bs            (lane = pixel, writes bank-distinct)
// Phase D: einsum, lane = channel. x reads = uniform base + lane (conflict-free b32);
//          wv reads = one b128 per tap, 4-distinct-address broadcast.
//          Sliding 4x7 register window: 70 x-reads instead of 196.
// Phase E: transpose via LDS (aliased over xs) -> coalesced global store.
__global__ __launch_bounds__(512, 4) void inv_kernel(
    const float* __restrict__ x, float* __restrict__ y,
    const float* __restrict__ wr, const float* __restrict__ br,
    const float* __restrict__ gam, const float* __restrict__ bet,
    const float* __restrict__ mu, const float* __restrict__ var,
    const float* __restrict__ wspan, const float* __restrict__ bspan)
{
  __shared__ __align__(16) char smem[63664];
  float* xs  = (float*)smem;                 // [140][65] = 36,400 B
  float* wvs = (float*)(smem + 36400);       // [4][49][8][4] = 25,088 B
  float* tss = (float*)(smem + 61488);       // [32][17] = 2,176 B
  float* ob  = (float*)smem;                 // [64][33] alias (after phase D)

  int tid = threadIdx.x;
  int bx = blockIdx.x & 15, by = blockIdx.x >> 4;
  int ox0 = bx * 8, oy0 = by * 4;
  int xh0 = ox0 - 3, yh0 = oy0 - 3;

  // ---- Phase A: stage x halo (14 cols x 10 rows x 64 ch), zero-padded
  for (int idx = tid; idx < 140 * 64; idx += 512) {
    int c = idx / 140;
    int pos = idx - c * 140;
    int row = pos / 14;
    int col = pos - row * 14;
    int gy = yh0 + row, gx = xh0 + col;
    float v = 0.f;
    if (gy >= 0 && gy < IH && gx >= 0 && gx < IW)
      v = x[c * HW + gy * IW + gx];
    xs[pos * 65 + c] = v;        // lanes: consecutive pos -> stride 65 -> free
  }
  __syncthreads();

  int w  = __builtin_amdgcn_readfirstlane(tid >> 6);  // wave id 0..7
  int ln = tid & 63;
  int p  = ln & 31;              // pixel 0..31 (row*8+col)
  int s  = ln >> 5;              // half 0/1

  // ---- Phase B: t = ReLU(BN(Wr.x)), one (pixel, cr) per thread
  {
    int cr = 2 * w + s;
    int prow = p >> 3, pcol = p & 7;
    int pos = (prow + 3) * 14 + (pcol + 3);
    const float* xr = &xs[pos * 65];
    const float* wrr = wr + cr * 64;
    float a = 0.f;
#pragma unroll
    for (int c = 0; c < 64; c++) a = fmaf(xr[c], wrr[c], a);
    float sc = gam[cr] * rsqrtf(var[cr] + 1e-5f);
    float t = (a + br[cr] - mu[cr]) * sc + bet[cr];
    tss[p * 17 + cr] = fmaxf(t, 0.f);
  }
  __syncthreads();

  // ---- Phase C: span. wave -> (g, k-half); lane -> (pixel, k-quarter)
  {
    int g  = w & 3;
    int q2 = (w >> 2) * 2 + s;   // k mod 4 class
    float t16[16];
#pragma unroll
    for (int i = 0; i < 16; i++) t16[i] = tss[p * 17 + i];
    int prow = p >> 3, pcol = p & 7;
    const float* wsb = wspan + g * 49 * 16;
    const float* bsb = bspan + g * 49;
    for (int k = q2; k < 49; k += 4) {
      const float* wk = wsb + k * 16;
      float a = bsb[k];
#pragma unroll
      for (int i = 0; i < 16; i++) a = fmaf(t16[i], wk[i], a);
      // [g][k][col][row]: lanes write distinct banks (col*4+row = 0..31)
      wvs[((g * 49 + k) * 8 + pcol) * 4 + prow] = a;
    }
  }
  __syncthreads();

  // ---- Phase D: einsum. wave = column strip w, lane = channel.
  float acc0 = 0.f, acc1 = 0.f, acc2 = 0.f, acc3 = 0.f;
  {
    int c = ln;
    int g = c >> 4;
    float xw[4][7];              // rows ky..ky+3 of the 7-col window
#pragma unroll
    for (int r = 0; r < 4; r++)
#pragma unroll
      for (int kx = 0; kx < 7; kx++)
        xw[r][kx] = xs[(r * 14 + w + kx) * 65 + c];   // uniform base + lane: free
#pragma unroll
    for (int ky = 0; ky < 7; ky++) {
      if (ky > 0) {
#pragma unroll
        for (int r = 0; r < 3; r++)
#pragma unroll
          for (int kx = 0; kx < 7; kx++) xw[r][kx] = xw[r + 1][kx];
#pragma unroll
        for (int kx = 0; kx < 7; kx++)
          xw[3][kx] = xs[((ky + 3) * 14 + w + kx) * 65 + c];
      }
#pragma unroll
      for (int kx = 0; kx < 7; kx++) {
        int k = ky * 7 + kx;
        float4 w4 = *(const float4*)&wvs[((g * 49 + k) * 8 + w) * 4];
        acc0 = fmaf(w4.x, xw[0][kx], acc0);
        acc1 = fmaf(w4.y, xw[1][kx], acc1);
        acc2 = fmaf(w4.z, xw[2][kx], acc2);
        acc3 = fmaf(w4.w, xw[3][kx], acc3);
      }
    }
  }
  __syncthreads();               // all xs reads done; safe to alias with ob

  // ---- Phase E: transpose via LDS, coalesced store (+outer ReLU)
  {
    int c = ln;
    ob[c * 33 + 0 * 8 + w] = fmaxf(acc0, 0.f);
    ob[c * 33 + 1 * 8 + w] = fmaxf(acc1, 0.f);
    ob[c * 33 + 2 * 8 + w] = fmaxf(acc2, 0.f);
    ob[c * 33 + 3 * 8 + w] = fmaxf(acc3, 0.f);
  }
  __syncthreads();
  for (int j = tid; j < 2048; j += 512) {
    int c = j >> 5, pp = j & 31;
    int prow = pp >> 3, pcol = pp & 7;
    int gy = oy0 + prow, gx = ox0 + pcol;
    if (gy < IH && gx < IW)
      y[c * HW + gy * IW + gx] = ob[c * 33 + pp];
  }
}

// ---------------------------------------------------------------- conv_out prep
// w (128,64,3,3) -> wt[k][ci][oc] so a wave's 8 output channels are contiguous.
__global__ __launch_bounds__(256) void transpose_w_kernel(
    const float* __restrict__ w, float* __restrict__ wt)
{
  int i = blockIdx.x * 256 + threadIdx.x;
  if (i >= 128 * 64 * 9) return;
  int oc = i / 576;
  int rem = i - oc * 576;
  int ci = rem / 9;
  int k = rem - ci * 9;
  wt[(k * 64 + ci) * 128 + oc] = w[i];
}

// ---------------------------------------------------------------- conv_out v2
// 8x8 tile, 64 och per block (8/wave via s_loads), grid (256,2) -> 2 blocks/CU.
// LDS [cq][pos][4]: b128 reads are lane-consecutive 16B units -> conflict-free.
__global__ __launch_bounds__(512, 4) void conv_out_kernel(
    const float* __restrict__ x, const float* __restrict__ wt,
    const float* __restrict__ b, float* __restrict__ y)
{
  __shared__ __align__(16) float xsm[16 * 100 * 4];   // 25,600 B
  int tid = threadIdx.x;
  int bx = blockIdx.x & 15, by = blockIdx.x >> 4;
  int oy0 = by * 8, ox0 = bx * 8;

  // stage: pack 4 channels -> one b128 write; lanes consecutive pos -> conflict-free
  for (int u = tid; u < 1600; u += 512) {
    int cq = u / 100;
    int pos = u - cq * 100;
    int row = pos / 10;
    int col = pos - row * 10;
    int gy = oy0 + row, gx = ox0 + col;
    float4 v = make_float4(0.f, 0.f, 0.f, 0.f);
    if (gy < IH && gx < IW) {
      const float* xp = x + cq * 4 * HW + gy * IW + gx;
      v.x = xp[0]; v.y = xp[HW]; v.z = xp[2 * HW]; v.w = xp[3 * HW];
    }
    *(float4*)&xsm[u * 4] = v;
  }
  __syncthreads();

  int ln = tid & 63;
  int px = ln & 7, py = ln >> 3;
  int wv_ = __builtin_amdgcn_readfirstlane(tid >> 6);   // wave 0..7
  int oc8 = blockIdx.y * 64 + wv_ * 8;

  float acc[8];
#pragma unroll
  for (int j = 0; j < 8; j++) acc[j] = b[oc8 + j];

#pragma unroll
  for (int ky = 0; ky < 3; ky++) {
#pragma unroll
    for (int kx = 0; kx < 3; kx++) {
      int k = ky * 3 + kx;
      int pidx = (py + ky) * 10 + px + kx;
      const float* wp = wt + k * 64 * 128 + oc8;   // uniform -> s_loads
#pragma unroll 4
      for (int cq = 0; cq < 16; cq++) {
        float4 xv = *(const float4*)&xsm[(cq * 100 + pidx) * 4];
        const float* wq = wp + cq * 4 * 128;
#pragma unroll
        for (int j = 0; j < 8; j++) {
          acc[j] = fmaf(xv.x, wq[0 * 128 + j], acc[j]);
          acc[j] = fmaf(xv.y, wq[1 * 128 + j], acc[j]);
          acc[j] = fmaf(xv.z, wq[2 * 128 + j], acc[j]);
          acc[j] = fmaf(xv.w, wq[3 * 128 + j], acc[j]);
        }
      }
    }
  }

  int oy = oy0 + py, ox = ox0 + px;
  if (oy < OH && ox < OW) {
#pragma unroll
    for (int j = 0; j < 8; j++)
      y[(oc8 + j) * OHW + oy * OW + ox] = acc[j];
  }
}

// ---------------------------------------------------------------- launch
extern "C" void kernel_launch(void* const* d_in, const int* in_sizes, int n_in,
                              void* d_out, int out_size, void* d_ws, size_t ws_size,
                              hipStream_t stream)
{
  const float* input = (const float*)d_in[0];
  const float* ciw   = (const float*)d_in[1];
  const float* cib   = (const float*)d_in[2];
  const float* wred  = (const float*)d_in[3];
  const float* bred  = (const float*)d_in[4];
  const float* gam   = (const float*)d_in[5];
  const float* bet   = (const float*)d_in[6];
  const float* mu    = (const float*)d_in[7];
  const float* var   = (const float*)d_in[8];
  const float* wspan = (const float*)d_in[9];
  const float* bspan = (const float*)d_in[10];
  const float* cow   = (const float*)d_in[11];
  const float* cob   = (const float*)d_in[12];
  float* out = (float*)d_out;

  float* bufA = (float*)d_ws;                 // 64*126*126 = 1,016,064 floats
  float* bufB = bufA + (1 << 20);             // @ 4 MiB
  float* wt   = bufA + (1 << 21);             // @ 8 MiB, 73,728 floats

  transpose_w_kernel<<<288, 256, 0, stream>>>(cow, wt);
  conv_in_kernel<<<dim3(63, 64), 256, 0, stream>>>(input, ciw, cib, bufA);

  float* cur = bufA; float* nxt = bufB;
  for (int i = 0; i < 6; i++) {
    inv_kernel<<<512, 512, 0, stream>>>(cur, nxt,
        wred + i * 16 * 64, bred + i * 16, gam + i * 16, bet + i * 16,
        mu + i * 16, var + i * 16, wspan + i * 196 * 16, bspan + i * 196);
    float* t = cur; cur = nxt; nxt = t;
  }
  conv_out_kernel<<<dim3(256, 2), 512, 0, stream>>>(cur, wt, cob, out);
}

// Round 3
// 253.221 us; speedup vs baseline: 1.1865x; 1.0055x over previous
//
#include <hip/hip_runtime.h>

#define IH 126
#define IW 126
#define HW 15876      // 126*126
#define OH 124
#define OW 124
#define OHW 15376     // 124*124

// ---------------------------------------------------------------- conv_in
__global__ __launch_bounds__(256) void conv_in_kernel(
    const float* __restrict__ x, const float* __restrict__ w,
    const float* __restrict__ b, float* __restrict__ y)
{
  int pix = blockIdx.x * 256 + threadIdx.x;
  if (pix >= HW) return;
  int oc = blockIdx.y;                 // wave-uniform -> weights become s_loads
  int h  = pix / IW;
  int wc = pix - h * IW;
  const float* wp = w + oc * 27;
  float acc = b[oc];
#pragma unroll
  for (int ci = 0; ci < 3; ci++)
#pragma unroll
    for (int ky = 0; ky < 3; ky++)
#pragma unroll
      for (int kx = 0; kx < 3; kx++)
        acc = fmaf(x[ci * 128 * 128 + (h + ky) * 128 + (wc + kx)],
                   wp[ci * 9 + ky * 3 + kx], acc);
  y[oc * HW + pix] = acc;
}

// ---------------------------------------------------------------- involution v3
// Tile 8x4, 512 blocks (2/CU), 512 threads. ALL weight reads wave-uniform
// (s_load from scalar cache) — no per-thread vector global loads.
//   xs[pos][68] pos-major: phase D reads = uniform base + lane (conflict-free);
//   phase B reads b128 over channels.
//   tss overlaid on wvs tail (extra barrier) -> LDS 63,168 B -> 2 blocks/CU.
__global__ __launch_bounds__(512, 4) void inv_kernel(
    const float* __restrict__ x, float* __restrict__ y,
    const float* __restrict__ wr, const float* __restrict__ br,
    const float* __restrict__ gam, const float* __restrict__ bet,
    const float* __restrict__ mu, const float* __restrict__ var,
    const float* __restrict__ wspan, const float* __restrict__ bspan)
{
  __shared__ __align__(16) float xs[140][68];   // 38,080 B; aliased by ob[64][33] in E
  __shared__ __align__(16) float wvs[6272];     // 25,088 B; tss = wvs[5632..] (2,560 B)
  float* tss = &wvs[5632];                      // [32][20]
  float* ob  = &xs[0][0];                       // [64][33] alias

  int tid = threadIdx.x;
  int bx = blockIdx.x & 15, by = blockIdx.x >> 4;
  int ox0 = bx * 8, oy0 = by * 4;
  int xh0 = ox0 - 3, yh0 = oy0 - 3;

  // ---- Phase A: stage x halo (14 cols x 10 rows x 64 ch), zero-padded
  for (int idx = tid; idx < 140 * 64; idx += 512) {
    int c = idx / 140;
    int pos = idx - c * 140;
    int row = pos / 14;
    int col = pos - row * 14;
    int gy = yh0 + row, gx = xh0 + col;
    float v = 0.f;
    if (gy >= 0 && gy < IH && gx >= 0 && gx < IW)
      v = x[c * HW + gy * IW + gx];
    xs[pos][c] = v;
  }
  __syncthreads();

  int w_ = __builtin_amdgcn_readfirstlane(tid >> 6);  // wave 0..7
  int ln = tid & 63;
  int p  = ln & 31;                   // pixel 0..31 (upper 32 lanes duplicate)
  int prow = p >> 3, pcol = p & 7;
  int pc = (prow + 3) * 14 + (pcol + 3);

  // ---- Phase B: t = ReLU(BN(Wr.x)); wave w_ does cr = 2w_, 2w_+1 (uniform)
  {
    int cr0 = 2 * w_;
    const float* wa = wr + cr0 * 64;  // uniform -> s_load
    const float* wb = wa + 64;
    float a0 = 0.f, a1 = 0.f;
#pragma unroll
    for (int ci = 0; ci < 64; ci += 4) {
      float4 xv = *(const float4*)&xs[pc][ci];
      a0 = fmaf(xv.x, wa[ci + 0], a0); a1 = fmaf(xv.x, wb[ci + 0], a1);
      a0 = fmaf(xv.y, wa[ci + 1], a0); a1 = fmaf(xv.y, wb[ci + 1], a1);
      a0 = fmaf(xv.z, wa[ci + 2], a0); a1 = fmaf(xv.z, wb[ci + 2], a1);
      a0 = fmaf(xv.w, wa[ci + 3], a0); a1 = fmaf(xv.w, wb[ci + 3], a1);
    }
    float s0 = gam[cr0]     * rsqrtf(var[cr0]     + 1e-5f);
    float s1 = gam[cr0 + 1] * rsqrtf(var[cr0 + 1] + 1e-5f);
    float t0 = (a0 + br[cr0]     - mu[cr0])     * s0 + bet[cr0];
    float t1 = (a1 + br[cr0 + 1] - mu[cr0 + 1]) * s1 + bet[cr0 + 1];
    if (ln < 32) {
      tss[p * 20 + cr0]     = fmaxf(t0, 0.f);
      tss[p * 20 + cr0 + 1] = fmaxf(t1, 0.f);
    }
  }
  __syncthreads();

  // ---- Phase C: span. wave w_ owns uniform pairs (g*49+k) = w_ + 8j.
  {
    float tv[16];
#pragma unroll
    for (int i = 0; i < 4; i++) {
      float4 t4 = *(const float4*)&tss[p * 20 + 4 * i];
      tv[4 * i] = t4.x; tv[4 * i + 1] = t4.y;
      tv[4 * i + 2] = t4.z; tv[4 * i + 3] = t4.w;
    }
    __syncthreads();                   // tss reads done; tail may be overwritten
    for (int j = 0; j < 25; j++) {
      int pair = w_ + 8 * j;           // wave-uniform
      if (pair < 196) {
        const float* wk = wspan + pair * 16;   // uniform -> s_load_dwordx16
        float a = bspan[pair];
#pragma unroll
        for (int i = 0; i < 16; i++) a = fmaf(tv[i], wk[i], a);
        if (ln < 32) wvs[pair * 32 + pcol * 4 + prow] = a;
      }
    }
  }
  __syncthreads();

  // ---- Phase D: einsum. wave = output column w_, lane = channel.
  float acc0 = 0.f, acc1 = 0.f, acc2 = 0.f, acc3 = 0.f;
  {
    int c = ln;
    int g = ln >> 4;
    float xw[4][7];
#pragma unroll
    for (int r = 0; r < 4; r++)
#pragma unroll
      for (int kx = 0; kx < 7; kx++)
        xw[r][kx] = xs[r * 14 + w_ + kx][c];   // uniform base + lane: conflict-free
#pragma unroll
    for (int ky = 0; ky < 7; ky++) {
      if (ky > 0) {
#pragma unroll
        for (int r = 0; r < 3; r++)
#pragma unroll
          for (int kx = 0; kx < 7; kx++) xw[r][kx] = xw[r + 1][kx];
#pragma unroll
        for (int kx = 0; kx < 7; kx++)
          xw[3][kx] = xs[(ky + 3) * 14 + w_ + kx][c];
      }
#pragma unroll
      for (int kx = 0; kx < 7; kx++) {
        int k = ky * 7 + kx;
        float4 w4 = *(const float4*)&wvs[(g * 49 + k) * 32 + w_ * 4];
        acc0 = fmaf(w4.x, xw[0][kx], acc0);
        acc1 = fmaf(w4.y, xw[1][kx], acc1);
        acc2 = fmaf(w4.z, xw[2][kx], acc2);
        acc3 = fmaf(w4.w, xw[3][kx], acc3);
      }
    }
  }
  __syncthreads();                     // xs reads done; safe to alias with ob

  // ---- Phase E: transpose via LDS, coalesced store (+outer ReLU)
  {
    int c = ln;
    ob[c * 33 + 0 * 8 + w_] = fmaxf(acc0, 0.f);
    ob[c * 33 + 1 * 8 + w_] = fmaxf(acc1, 0.f);
    ob[c * 33 + 2 * 8 + w_] = fmaxf(acc2, 0.f);
    ob[c * 33 + 3 * 8 + w_] = fmaxf(acc3, 0.f);
  }
  __syncthreads();
  for (int j = tid; j < 2048; j += 512) {
    int c2 = j >> 5, pp = j & 31;
    int pr = pp >> 3, pc2 = pp & 7;
    int gy = oy0 + pr, gx = ox0 + pc2;
    if (gy < IH && gx < IW)
      y[c2 * HW + gy * IW + gx] = ob[c2 * 33 + pp];
  }
}

// ---------------------------------------------------------------- conv_out prep
__global__ __launch_bounds__(256) void transpose_w_kernel(
    const float* __restrict__ w, float* __restrict__ wt)
{
  int i = blockIdx.x * 256 + threadIdx.x;
  if (i >= 128 * 64 * 9) return;
  int oc = i / 576;
  int rem = i - oc * 576;
  int ci = rem / 9;
  int k = rem - ci * 9;
  wt[(k * 64 + ci) * 128 + oc] = w[i];
}

// ---------------------------------------------------------------- conv_out v3
// Same stream as v2 but 256-thread blocks, grid (256 tiles, 4 oc-groups):
// 6 blocks/CU (LDS 25.6 KB) = 24 waves/CU — block-level parallelism hides the
// s_load weight-fetch latency chains that stalled v2 (VALUBusy 35%).
__global__ __launch_bounds__(256, 6) void conv_out_kernel(
    const float* __restrict__ x, const float* __restrict__ wt,
    const float* __restrict__ b, float* __restrict__ y)
{
  __shared__ __align__(16) float xsm[16 * 100 * 4];   // 25,600 B
  int tid = threadIdx.x;
  int bx = blockIdx.x & 15, by = blockIdx.x >> 4;
  int oy0 = by * 8, ox0 = bx * 8;

  for (int u = tid; u < 1600; u += 256) {
    int cq = u / 100;
    int pos = u - cq * 100;
    int row = pos / 10;
    int col = pos - row * 10;
    int gy = oy0 + row, gx = ox0 + col;
    float4 v = make_float4(0.f, 0.f, 0.f, 0.f);
    if (gy < IH && gx < IW) {
      const float* xp = x + cq * 4 * HW + gy * IW + gx;
      v.x = xp[0]; v.y = xp[HW]; v.z = xp[2 * HW]; v.w = xp[3 * HW];
    }
    *(float4*)&xsm[u * 4] = v;
  }
  __syncthreads();

  int ln = tid & 63;
  int px = ln & 7, py = ln >> 3;
  int wv_ = __builtin_amdgcn_readfirstlane(tid >> 6);   // wave 0..3
  int oc8 = blockIdx.y * 32 + wv_ * 8;

  float acc[8];
#pragma unroll
  for (int j = 0; j < 8; j++) acc[j] = b[oc8 + j];

#pragma unroll
  for (int ky = 0; ky < 3; ky++) {
#pragma unroll
    for (int kx = 0; kx < 3; kx++) {
      int k = ky * 3 + kx;
      int pidx = (py + ky) * 10 + px + kx;
      const float* wp = wt + k * 64 * 128 + oc8;   // uniform -> s_loads
#pragma unroll 4
      for (int cq = 0; cq < 16; cq++) {
        float4 xv = *(const float4*)&xsm[(cq * 100 + pidx) * 4];
        const float* wq = wp + cq * 4 * 128;
#pragma unroll
        for (int j = 0; j < 8; j++) {
          acc[j] = fmaf(xv.x, wq[0 * 128 + j], acc[j]);
          acc[j] = fmaf(xv.y, wq[1 * 128 + j], acc[j]);
          acc[j] = fmaf(xv.z, wq[2 * 128 + j], acc[j]);
          acc[j] = fmaf(xv.w, wq[3 * 128 + j], acc[j]);
        }
      }
    }
  }

  int oy = oy0 + py, ox = ox0 + px;
  if (oy < OH && ox < OW) {
#pragma unroll
    for (int j = 0; j < 8; j++)
      y[(oc8 + j) * OHW + oy * OW + ox] = acc[j];
  }
}

// ---------------------------------------------------------------- launch
extern "C" void kernel_launch(void* const* d_in, const int* in_sizes, int n_in,
                              void* d_out, int out_size, void* d_ws, size_t ws_size,
                              hipStream_t stream)
{
  const float* input = (const float*)d_in[0];
  const float* ciw   = (const float*)d_in[1];
  const float* cib   = (const float*)d_in[2];
  const float* wred  = (const float*)d_in[3];
  const float* bred  = (const float*)d_in[4];
  const float* gam   = (const float*)d_in[5];
  const float* bet   = (const float*)d_in[6];
  const float* mu    = (const float*)d_in[7];
  const float* var   = (const float*)d_in[8];
  const float* wspan = (const float*)d_in[9];
  const float* bspan = (const float*)d_in[10];
  const float* cow   = (const float*)d_in[11];
  const float* cob   = (const float*)d_in[12];
  float* out = (float*)d_out;

  float* bufA = (float*)d_ws;                 // 64*126*126 = 1,016,064 floats
  float* bufB = bufA + (1 << 20);             // @ 4 MiB
  float* wt   = bufA + (1 << 21);             // @ 8 MiB, 73,728 floats

  transpose_w_kernel<<<288, 256, 0, stream>>>(cow, wt);
  conv_in_kernel<<<dim3(63, 64), 256, 0, stream>>>(input, ciw, cib, bufA);

  float* cur = bufA; float* nxt = bufB;
  for (int i = 0; i < 6; i++) {
    inv_kernel<<<512, 512, 0, stream>>>(cur, nxt,
        wred + i * 16 * 64, bred + i * 16, gam + i * 16, bet + i * 16,
        mu + i * 16, var + i * 16, wspan + i * 196 * 16, bspan + i * 196);
    float* t = cur; cur = nxt; nxt = t;
  }
  conv_out_kernel<<<dim3(256, 4), 256, 0, stream>>>(cur, wt, cob, out);
}